// Round 5
// baseline (122.751 us; speedup 1.0000x reference)
//
#include <hip/hip_runtime.h>

// Double-sparse matvec: y = A @ (B @ x), ELL form.
// M=N=K=8192, NNZ=256 per row, BATCH=32, fp32 in/out.
//
// R5: gathers are L2-random-line-throughput bound (268 MB of 128B lines per
// stage). Halve gathered bytes by gathering fp16: x converted once to fp16,
// bx stored fp16; accumulation stays fp32. Gather = 8B/lane dwordx2, 8
// distinct fully-used 64B lines per wave-instruction.
//
// Stage 0: x16 = (fp16)x                                  -> d_ws + 512K
// Stage 1: bx16[k][b] = sum_j b_vals[k][j] * x16[b_idx[k][j]][b]  -> d_ws
// Stage 2: out[b*M+m] = sum_j a_vals[m][j] * bx16[a_idx[m][j]][b]
//
// Lane layout: lane = q*8 + s.
//   s in [0,8): batch quad — 4 batch columns [4s,4s+4) per lane
//   q in [0,8): owns consecutive index block j = q*32 .. q*32+31

#define NNZ    256
#define BATCH  32
#define ROWS   8192

typedef int      vi4 __attribute__((ext_vector_type(4)));
typedef float    vf4 __attribute__((ext_vector_type(4)));
typedef _Float16 vh4 __attribute__((ext_vector_type(4)));

// ---- Stage 0: fp32 -> fp16 convert of x ([ROWS][BATCH], 256K elems) ----
__global__ __launch_bounds__(256) void cvt_f32_f16(
    const float* __restrict__ src, _Float16* __restrict__ dst)
{
    const int i = blockIdx.x * 256 + threadIdx.x;   // 4 elems per thread
    const vf4 v = *(const vf4*)(src + i * 4);
    vh4 h;
    h.x = (_Float16)v.x; h.y = (_Float16)v.y;
    h.z = (_Float16)v.z; h.w = (_Float16)v.w;
    *(vh4*)(dst + i * 4) = h;
}

// ---- Stages 1/2: ELL spmv with fp16 gathers, fp32 accumulate ----
// OUT16: write [ROWS][BATCH] fp16 (stage 1). Else fp32 transposed [BATCH][ROWS].
template <bool OUT16>
__global__ __launch_bounds__(256) void ell_spmv_h(
    const int*      __restrict__ idx,   // [ROWS, NNZ]
    const float*    __restrict__ vals,  // [ROWS, NNZ]
    const _Float16* __restrict__ src,   // [src_rows, BATCH] fp16
    _Float16*       __restrict__ dst16, // [ROWS, BATCH] fp16   (OUT16)
    float*          __restrict__ dst32) // [BATCH, ROWS] fp32   (!OUT16)
{
    __shared__ float tile[4][BATCH];            // only used when !OUT16

    const int wave = threadIdx.x >> 6;          // 0..3
    const int lane = threadIdx.x & 63;
    const int r    = blockIdx.x * 4 + wave;     // sparse row
    const int s    = lane & 7;                  // batch quad id
    const int q    = lane >> 3;                 // consecutive index block of 32

    const vi4* i4 = (const vi4*)(idx  + r * NNZ) + q * 8;
    const vf4* v4 = (const vf4*)(vals + r * NNZ) + q * 8;
    const int  soff = s * 4;

    vf4 acc = {0.f, 0.f, 0.f, 0.f};

    #pragma unroll
    for (int t = 0; t < 8; ++t) {
        const vi4 iv = __builtin_nontemporal_load(i4 + t);   // stream once
        const vf4 vv = __builtin_nontemporal_load(v4 + t);
        {
            const vh4 xv = *(const vh4*)(src + iv.x * BATCH + soff);  // 8B gather
            acc.x += vv.x * (float)xv.x; acc.y += vv.x * (float)xv.y;
            acc.z += vv.x * (float)xv.z; acc.w += vv.x * (float)xv.w;
        }
        {
            const vh4 xv = *(const vh4*)(src + iv.y * BATCH + soff);
            acc.x += vv.y * (float)xv.x; acc.y += vv.y * (float)xv.y;
            acc.z += vv.y * (float)xv.z; acc.w += vv.y * (float)xv.w;
        }
        {
            const vh4 xv = *(const vh4*)(src + iv.z * BATCH + soff);
            acc.x += vv.z * (float)xv.x; acc.y += vv.z * (float)xv.y;
            acc.z += vv.z * (float)xv.z; acc.w += vv.z * (float)xv.w;
        }
        {
            const vh4 xv = *(const vh4*)(src + iv.w * BATCH + soff);
            acc.x += vv.w * (float)xv.x; acc.y += vv.w * (float)xv.y;
            acc.z += vv.w * (float)xv.z; acc.w += vv.w * (float)xv.w;
        }
    }

    // reduce across the 8 q-blocks (lanes strided by 8): xor 8, 16, 32
    #pragma unroll
    for (int d = 8; d < 64; d <<= 1) {
        acc.x += __shfl_xor(acc.x, d);
        acc.y += __shfl_xor(acc.y, d);
        acc.z += __shfl_xor(acc.z, d);
        acc.w += __shfl_xor(acc.w, d);
    }

    if (OUT16) {
        if (q == 0) {                               // lanes 0..7: 64B coalesced
            vh4 h;
            h.x = (_Float16)acc.x; h.y = (_Float16)acc.y;
            h.z = (_Float16)acc.z; h.w = (_Float16)acc.w;
            *(vh4*)(dst16 + r * BATCH + soff) = h;
        }
    } else {
        if (q == 0)
            *(vf4*)(&tile[wave][soff]) = acc;
        __syncthreads();
        // out[b*ROWS + r0 + rr]: 16B-contiguous segments per batch row
        const int t = threadIdx.x;
        if (t < 4 * BATCH) {
            const int b  = t >> 2;
            const int rr = t & 3;
            __builtin_nontemporal_store(tile[rr][b],
                                        dst32 + b * ROWS + blockIdx.x * 4 + rr);
        }
    }
}

extern "C" void kernel_launch(void* const* d_in, const int* in_sizes, int n_in,
                              void* d_out, int out_size, void* d_ws, size_t ws_size,
                              hipStream_t stream) {
    // setup_inputs order: x, a_idx, a_vals, b_idx, b_vals
    const float* x      = (const float*)d_in[0];   // [N, BATCH]
    const int*   a_idx  = (const int*)  d_in[1];   // [M, NNZ]
    const float* a_vals = (const float*)d_in[2];   // [M, NNZ]
    const int*   b_idx  = (const int*)  d_in[3];   // [K, NNZ]
    const float* b_vals = (const float*)d_in[4];   // [K, NNZ]
    float*       out    = (float*)d_out;           // [BATCH, M] fp32

    _Float16* bx16 = (_Float16*)d_ws;                       // 512 KB
    _Float16* x16  = (_Float16*)d_ws + (size_t)ROWS * BATCH; // 512 KB

    dim3 block(256);

    // Stage 0: convert x to fp16 (262144 elems, 4/thread)
    cvt_f32_f16<<<dim3(ROWS * BATCH / 4 / 256), block, 0, stream>>>(x, x16);
    // Stage 1: bx16 = B @ x
    ell_spmv_h<true ><<<dim3(ROWS / 4), block, 0, stream>>>(
        b_idx, b_vals, x16, bx16, nullptr);
    // Stage 2: out = A @ bx (transposed store)
    ell_spmv_h<false><<<dim3(ROWS / 4), block, 0, stream>>>(
        a_idx, a_vals, bx16, nullptr, out);
}

// Round 6
// 112.502 us; speedup vs baseline: 1.0911x; 1.0911x over previous
//
#include <hip/hip_runtime.h>

// Double-sparse matvec: y = A @ (B @ x), ELL form.
// M=N=K=8192, NNZ=256 per row, BATCH=32, fp32 in/out.
//
// R6: 16-distinct-index gathers. fp16 batch row = 64 B = 4 lanes x 16 B,
// so one gather instruction services 16 indices (vs 8). Per row:
//   4 int4 idx + 4 float4 vals + 16 vh8 gathers = 24 VMEM instrs
// (R5 was 48). Segments/row unchanged (256) — this round discriminates
// VMEM-issue-bound vs segment/harness floor.
//
// Stage 0: x16 = (fp16)x                                   -> ws + 512K
// Stage 1: bx16[k][b] = sum_j b_vals[k][j] * x16[b_idx[k][j]][b] -> ws
// Stage 2: out[b*M+m] = sum_j a_vals[m][j] * bx16[a_idx[m][j]][b]
//
// Lane layout: lane = q*4 + s.
//   s in [0,4): batch octet — 8 fp16 batch columns [8s, 8s+8) per lane
//   q in [0,16): owns consecutive nnz block j = q*16 .. q*16+15

#define NNZ    256
#define BATCH  32
#define ROWS   8192

typedef int      vi4 __attribute__((ext_vector_type(4)));
typedef float    vf4 __attribute__((ext_vector_type(4)));
typedef _Float16 vh4 __attribute__((ext_vector_type(4)));
typedef _Float16 vh8 __attribute__((ext_vector_type(8)));

// ---- Stage 0: fp32 -> fp16 convert of x ([ROWS][BATCH], 256K elems) ----
__global__ __launch_bounds__(256) void cvt_f32_f16(
    const float* __restrict__ src, _Float16* __restrict__ dst)
{
    const int i = blockIdx.x * 256 + threadIdx.x;   // 4 elems per thread
    const vf4 v = *(const vf4*)(src + i * 4);
    vh4 h;
    h.x = (_Float16)v.x; h.y = (_Float16)v.y;
    h.z = (_Float16)v.z; h.w = (_Float16)v.w;
    *(vh4*)(dst + i * 4) = h;
}

// ---- Stages 1/2: ELL spmv, fp16 gathers 16B/lane, fp32 accumulate ----
template <bool OUT16>
__global__ __launch_bounds__(256) void ell_spmv_h(
    const int*      __restrict__ idx,   // [ROWS, NNZ]
    const float*    __restrict__ vals,  // [ROWS, NNZ]
    const _Float16* __restrict__ src,   // [src_rows, BATCH] fp16
    _Float16*       __restrict__ dst16, // [ROWS, BATCH] fp16   (OUT16)
    float*          __restrict__ dst32) // [BATCH, ROWS] fp32   (!OUT16)
{
    __shared__ float tile[4][BATCH];            // only used when !OUT16

    const int wave = threadIdx.x >> 6;          // 0..3
    const int lane = threadIdx.x & 63;
    const int r    = blockIdx.x * 4 + wave;     // sparse row
    const int s    = lane & 3;                  // batch octet id
    const int q    = lane >> 2;                 // consecutive nnz block of 16

    const vi4* i4 = (const vi4*)(idx  + r * NNZ) + q * 4;
    const vf4* v4 = (const vf4*)(vals + r * NNZ) + q * 4;
    const int  soff = s * 8;

    float acc[8] = {0.f, 0.f, 0.f, 0.f, 0.f, 0.f, 0.f, 0.f};

    #pragma unroll
    for (int t = 0; t < 4; ++t) {
        const vi4 iv = __builtin_nontemporal_load(i4 + t);   // lane-owned idx
        const vf4 vv = __builtin_nontemporal_load(v4 + t);
        {
            const vh8 xv = *(const vh8*)(src + iv.x * BATCH + soff);  // 16B gather
            #pragma unroll
            for (int j = 0; j < 8; ++j) acc[j] += vv.x * (float)xv[j];
        }
        {
            const vh8 xv = *(const vh8*)(src + iv.y * BATCH + soff);
            #pragma unroll
            for (int j = 0; j < 8; ++j) acc[j] += vv.y * (float)xv[j];
        }
        {
            const vh8 xv = *(const vh8*)(src + iv.z * BATCH + soff);
            #pragma unroll
            for (int j = 0; j < 8; ++j) acc[j] += vv.z * (float)xv[j];
        }
        {
            const vh8 xv = *(const vh8*)(src + iv.w * BATCH + soff);
            #pragma unroll
            for (int j = 0; j < 8; ++j) acc[j] += vv.w * (float)xv[j];
        }
    }

    // reduce across the 16 q-blocks (lanes strided by 4): xor 4, 8, 16, 32
    #pragma unroll
    for (int d = 4; d < 64; d <<= 1) {
        #pragma unroll
        for (int j = 0; j < 8; ++j) acc[j] += __shfl_xor(acc[j], d);
    }

    if (OUT16) {
        if (q == 0) {                               // lanes 0..3: 64B coalesced
            vh8 h;
            #pragma unroll
            for (int j = 0; j < 8; ++j) h[j] = (_Float16)acc[j];
            *(vh8*)(dst16 + r * BATCH + soff) = h;
        }
    } else {
        if (q == 0) {
            #pragma unroll
            for (int j = 0; j < 8; ++j) tile[wave][soff + j] = acc[j];
        }
        __syncthreads();
        // out[b*ROWS + r0 + rr]: 16B-contiguous segments per batch row
        const int t = threadIdx.x;
        if (t < 4 * BATCH) {
            const int b  = t >> 2;
            const int rr = t & 3;
            __builtin_nontemporal_store(tile[rr][b],
                                        dst32 + b * ROWS + blockIdx.x * 4 + rr);
        }
    }
}

extern "C" void kernel_launch(void* const* d_in, const int* in_sizes, int n_in,
                              void* d_out, int out_size, void* d_ws, size_t ws_size,
                              hipStream_t stream) {
    // setup_inputs order: x, a_idx, a_vals, b_idx, b_vals
    const float* x      = (const float*)d_in[0];   // [N, BATCH]
    const int*   a_idx  = (const int*)  d_in[1];   // [M, NNZ]
    const float* a_vals = (const float*)d_in[2];   // [M, NNZ]
    const int*   b_idx  = (const int*)  d_in[3];   // [K, NNZ]
    const float* b_vals = (const float*)d_in[4];   // [K, NNZ]
    float*       out    = (float*)d_out;           // [BATCH, M] fp32

    _Float16* bx16 = (_Float16*)d_ws;                        // 512 KB
    _Float16* x16  = (_Float16*)d_ws + (size_t)ROWS * BATCH; // 512 KB

    dim3 block(256);

    // Stage 0: convert x to fp16 (262144 elems, 4/thread)
    cvt_f32_f16<<<dim3(ROWS * BATCH / 4 / 256), block, 0, stream>>>(x, x16);
    // Stage 1: bx16 = B @ x
    ell_spmv_h<true ><<<dim3(ROWS / 4), block, 0, stream>>>(
        b_idx, b_vals, x16, bx16, nullptr);
    // Stage 2: out = A @ bx (transposed store)
    ell_spmv_h<false><<<dim3(ROWS / 4), block, 0, stream>>>(
        a_idx, a_vals, bx16, nullptr, out);
}

// Round 7
// 110.234 us; speedup vs baseline: 1.1135x; 1.0206x over previous
//
#include <hip/hip_runtime.h>

// Double-sparse matvec: y = A @ (B @ x), ELL form.
// M=N=K=8192, NNZ=256 per row, BATCH=32, fp32 in/out.
//
// R7: packed-fp16 accumulation. R6 showed gathers are at the byte floor
// (16 instrs/row = 16KB/row / 1KB-per-instr); the remaining co-binder is
// VALU: 16 scalar (cvt+fma) ops per index. Replace with 4 v_pk_fma_f16 per
// index (acc in fp16 pairs, converted to fp32 after the loop). 4x VALU cut
// in the hot loop; vals also quantized to fp16 (rel 2^-11, negligible).
//
// Stage 0: x16 = (fp16)x                                   -> ws + 512K
// Stage 1: bx16[k][b] = sum_j b_vals[k][j] * x16[b_idx[k][j]][b] -> ws
// Stage 2: out[b*M+m] = sum_j a_vals[m][j] * bx16[a_idx[m][j]][b]
//
// Lane layout: lane = q*4 + s.
//   s in [0,4): batch octet — 8 fp16 batch columns [8s, 8s+8) per lane
//   q in [0,16): owns consecutive nnz block j = q*16 .. q*16+15

#define NNZ    256
#define BATCH  32
#define ROWS   8192

typedef int      vi4 __attribute__((ext_vector_type(4)));
typedef float    vf4 __attribute__((ext_vector_type(4)));
typedef _Float16 vh4 __attribute__((ext_vector_type(4)));
typedef _Float16 vh8 __attribute__((ext_vector_type(8)));

// ---- Stage 0: fp32 -> fp16 convert of x ([ROWS][BATCH], 256K elems) ----
__global__ __launch_bounds__(256) void cvt_f32_f16(
    const float* __restrict__ src, _Float16* __restrict__ dst)
{
    const int i = blockIdx.x * 256 + threadIdx.x;   // 4 elems per thread
    const vf4 v = *(const vf4*)(src + i * 4);
    vh4 h;
    h.x = (_Float16)v.x; h.y = (_Float16)v.y;
    h.z = (_Float16)v.z; h.w = (_Float16)v.w;
    *(vh4*)(dst + i * 4) = h;
}

// ---- Stages 1/2: ELL spmv, fp16 gathers, packed-fp16 accumulate ----
template <bool OUT16>
__global__ __launch_bounds__(256) void ell_spmv_h(
    const int*      __restrict__ idx,   // [ROWS, NNZ]
    const float*    __restrict__ vals,  // [ROWS, NNZ]
    const _Float16* __restrict__ src,   // [src_rows, BATCH] fp16
    _Float16*       __restrict__ dst16, // [ROWS, BATCH] fp16   (OUT16)
    float*          __restrict__ dst32) // [BATCH, ROWS] fp32   (!OUT16)
{
    __shared__ float tile[4][BATCH];            // only used when !OUT16

    const int wave = threadIdx.x >> 6;          // 0..3
    const int lane = threadIdx.x & 63;
    const int r    = blockIdx.x * 4 + wave;     // sparse row
    const int s    = lane & 3;                  // batch octet id
    const int q    = lane >> 2;                 // consecutive nnz block of 16

    const vi4* i4 = (const vi4*)(idx  + r * NNZ) + q * 4;
    const vf4* v4 = (const vf4*)(vals + r * NNZ) + q * 4;
    const int  soff = s * 8;

    vh8 acc = {0, 0, 0, 0, 0, 0, 0, 0};        // fp16 packed accumulators

    #pragma unroll
    for (int t = 0; t < 4; ++t) {
        const vi4 iv = __builtin_nontemporal_load(i4 + t);   // lane-owned idx
        const vf4 vv = __builtin_nontemporal_load(v4 + t);
        const _Float16 h0 = (_Float16)vv.x, h1 = (_Float16)vv.y;
        const _Float16 h2 = (_Float16)vv.z, h3 = (_Float16)vv.w;
        {
            const vh8 xv = *(const vh8*)(src + iv.x * BATCH + soff);  // 16B gather
            const vh8 b = {h0, h0, h0, h0, h0, h0, h0, h0};
            acc += b * xv;                       // 4x v_pk_fma_f16
        }
        {
            const vh8 xv = *(const vh8*)(src + iv.y * BATCH + soff);
            const vh8 b = {h1, h1, h1, h1, h1, h1, h1, h1};
            acc += b * xv;
        }
        {
            const vh8 xv = *(const vh8*)(src + iv.z * BATCH + soff);
            const vh8 b = {h2, h2, h2, h2, h2, h2, h2, h2};
            acc += b * xv;
        }
        {
            const vh8 xv = *(const vh8*)(src + iv.w * BATCH + soff);
            const vh8 b = {h3, h3, h3, h3, h3, h3, h3, h3};
            acc += b * xv;
        }
    }

    // widen to fp32, then reduce across the 16 q-blocks: xor 4, 8, 16, 32
    float a32[8];
    #pragma unroll
    for (int j = 0; j < 8; ++j) a32[j] = (float)acc[j];

    #pragma unroll
    for (int d = 4; d < 64; d <<= 1) {
        #pragma unroll
        for (int j = 0; j < 8; ++j) a32[j] += __shfl_xor(a32[j], d);
    }

    if (OUT16) {
        if (q == 0) {                               // lanes 0..3: 64B coalesced
            vh8 h;
            #pragma unroll
            for (int j = 0; j < 8; ++j) h[j] = (_Float16)a32[j];
            *(vh8*)(dst16 + r * BATCH + soff) = h;
        }
    } else {
        if (q == 0) {
            #pragma unroll
            for (int j = 0; j < 8; ++j) tile[wave][soff + j] = a32[j];
        }
        __syncthreads();
        // out[b*ROWS + r0 + rr]: 16B-contiguous segments per batch row
        const int t = threadIdx.x;
        if (t < 4 * BATCH) {
            const int b  = t >> 2;
            const int rr = t & 3;
            __builtin_nontemporal_store(tile[rr][b],
                                        dst32 + b * ROWS + blockIdx.x * 4 + rr);
        }
    }
}

extern "C" void kernel_launch(void* const* d_in, const int* in_sizes, int n_in,
                              void* d_out, int out_size, void* d_ws, size_t ws_size,
                              hipStream_t stream) {
    // setup_inputs order: x, a_idx, a_vals, b_idx, b_vals
    const float* x      = (const float*)d_in[0];   // [N, BATCH]
    const int*   a_idx  = (const int*)  d_in[1];   // [M, NNZ]
    const float* a_vals = (const float*)d_in[2];   // [M, NNZ]
    const int*   b_idx  = (const int*)  d_in[3];   // [K, NNZ]
    const float* b_vals = (const float*)d_in[4];   // [K, NNZ]
    float*       out    = (float*)d_out;           // [BATCH, M] fp32

    _Float16* bx16 = (_Float16*)d_ws;                        // 512 KB
    _Float16* x16  = (_Float16*)d_ws + (size_t)ROWS * BATCH; // 512 KB

    dim3 block(256);

    // Stage 0: convert x to fp16 (262144 elems, 4/thread)
    cvt_f32_f16<<<dim3(ROWS * BATCH / 4 / 256), block, 0, stream>>>(x, x16);
    // Stage 1: bx16 = B @ x
    ell_spmv_h<true ><<<dim3(ROWS / 4), block, 0, stream>>>(
        b_idx, b_vals, x16, bx16, nullptr);
    // Stage 2: out = A @ bx (transposed store)
    ell_spmv_h<false><<<dim3(ROWS / 4), block, 0, stream>>>(
        a_idx, a_vals, bx16, nullptr, out);
}